// Round 1
// baseline (556.463 us; speedup 1.0000x reference)
//
#include <hip/hip_runtime.h>
#include <math.h>

// Problem constants (fixed by the reference):
//   N=200000, D=1000, C=16, E=4
static constexpr int CT = 16;     // celltypes
static constexpr int ET = 4;      // embedding dim
static constexpr float EXPANSION = 2.0f;
static constexpr float MAX_RANGE = 5.65486677646163f;  // 2*pi*0.9

// Workspace layout (float units), D=1000 fixed:
//  [0,16000)        w0[c][d]
//  [16000,32000)    w1[c][d]
//  [32000,32032)    const_c[c][2]
//  [32032,32048)    angle_mean[c]
//  [32048,32064)    ratio[c]
//  [32064,32080)    keep[c]
//  [32080,32096)    cnt[c]
//  [32096,32128)    minmax enc (unsigned) [2c]=min-enc, [2c+1]=max-enc
//  [32128, 32128+2N)      pcn[r][2]
//  [.. +N)                dev[r]
//  [.. +NW*48)            wave partials [wave][c][3] = sx,sy,cnt
static constexpr int OFF_W0 = 0;
static constexpr int OFF_W1 = 16000;
static constexpr int OFF_CONST = 32000;
static constexpr int OFF_AMEAN = 32032;
static constexpr int OFF_RATIO = 32048;
static constexpr int OFF_KEEP = 32064;
static constexpr int OFF_CNT = 32080;
static constexpr int OFF_MINMAX = 32096;   // 32 unsigned
static constexpr int OFF_PCN = 32128;

static constexpr int NB_HEAVY = 1024;      // blocks for K2/K6 (4 waves each)
static constexpr int NW = NB_HEAVY * 4;    // wave count in K2

// order-preserving float<->uint map for atomic min/max
__device__ __forceinline__ unsigned fenc(float f) {
  unsigned u = __float_as_uint(f);
  return (u & 0x80000000u) ? ~u : (u | 0x80000000u);
}
__device__ __forceinline__ float fdec(unsigned e) {
  unsigned u = (e & 0x80000000u) ? (e ^ 0x80000000u) : ~e;
  return __uint_as_float(u);
}

// K1: per-celltype effective weights + constants; init minmax slots.
__global__ void k1_setup(const float* __restrict__ emb, const float* __restrict__ Ws,
                         const float* __restrict__ bs, const float* __restrict__ Wa,
                         const float* __restrict__ ba, const float* __restrict__ gb,
                         const float* __restrict__ We, const float* __restrict__ be,
                         float* __restrict__ ws, int D) {
  int c = blockIdx.x;
  float e0 = emb[c * ET + 0], e1 = emb[c * ET + 1], e2 = emb[c * ET + 2], e3 = emb[c * ET + 3];
  float a0 = 0.f, a1 = 0.f;
  for (int d = threadIdx.x; d < D; d += blockDim.x) {
    float sc = e0 * Ws[d] + e1 * Ws[D + d] + e2 * Ws[2 * D + d] + e3 * Ws[3 * D + d] + bs[d];
    float ad = e0 * Wa[d] + e1 * Wa[D + d] + e2 * Wa[2 * D + d] + e3 * Wa[3 * D + d] + ba[d];
    float s1 = 1.f + sc;
    float we0 = We[2 * d], we1 = We[2 * d + 1];
    ws[OFF_W0 + c * D + d] = s1 * we0;
    ws[OFF_W1 + c * D + d] = s1 * we1;
    float t = ad + gb[d];
    a0 += t * we0;
    a1 += t * we1;
  }
  __shared__ float r0[256], r1[256];
  r0[threadIdx.x] = a0;
  r1[threadIdx.x] = a1;
  __syncthreads();
  for (int s = 128; s > 0; s >>= 1) {
    if ((int)threadIdx.x < s) {
      r0[threadIdx.x] += r0[threadIdx.x + s];
      r1[threadIdx.x] += r1[threadIdx.x + s];
    }
    __syncthreads();
  }
  if (threadIdx.x == 0) {
    ws[OFF_CONST + c * 2 + 0] = r0[0] + be[0];
    ws[OFF_CONST + c * 2 + 1] = r1[0] + be[1];
  }
  if (blockIdx.x == 0 && threadIdx.x < CT) {
    unsigned* mm = (unsigned*)(ws + OFF_MINMAX);
    mm[2 * threadIdx.x] = 0xFFFFFFFFu;     // min-enc init (= +inf side)
    mm[2 * threadIdx.x + 1] = 0u;          // max-enc init (= -inf side)
  }
}

// K2: wave-per-row dot products -> pcn; deterministic per-wave segment partials.
__global__ __launch_bounds__(256) void k2_pc(const float* __restrict__ x,
                                             const int* __restrict__ ct,
                                             float* __restrict__ ws, int N, int D) {
  const int lane = threadIdx.x & 63;
  const int wid = (int)((blockIdx.x * blockDim.x + threadIdx.x) >> 6);
  const int nw = (int)((gridDim.x * blockDim.x) >> 6);
  const int D4 = D >> 2;
  const float* constc = ws + OFF_CONST;
  float2* pcn = (float2*)(ws + OFF_PCN);

  float sx = 0.f, sy = 0.f, scnt = 0.f;  // valid on lane==c only
  for (int r = wid; r < N; r += nw) {
    int c = ct[r];
    const float4* xr = (const float4*)(x + (size_t)r * D);
    const float4* w0r = (const float4*)(ws + OFF_W0 + (size_t)c * D);
    const float4* w1r = (const float4*)(ws + OFF_W1 + (size_t)c * D);
    float a0 = 0.f, a1 = 0.f;
    for (int j = lane; j < D4; j += 64) {
      float4 xv = xr[j];
      float4 v0 = w0r[j];
      float4 v1 = w1r[j];
      a0 = fmaf(xv.x, v0.x, a0); a0 = fmaf(xv.y, v0.y, a0);
      a0 = fmaf(xv.z, v0.z, a0); a0 = fmaf(xv.w, v0.w, a0);
      a1 = fmaf(xv.x, v1.x, a1); a1 = fmaf(xv.y, v1.y, a1);
      a1 = fmaf(xv.z, v1.z, a1); a1 = fmaf(xv.w, v1.w, a1);
    }
    for (int off = 32; off; off >>= 1) {
      a0 += __shfl_xor(a0, off, 64);
      a1 += __shfl_xor(a1, off, 64);
    }
    float p0 = a0 + constc[2 * c], p1 = a1 + constc[2 * c + 1];
    float nrm = sqrtf(p0 * p0 + p1 * p1) + 1e-8f;
    float q0 = p0 / nrm, q1 = p1 / nrm;
    if (lane == 0) pcn[r] = make_float2(q0, q1);
    if (lane == c) { sx += q0; sy += q1; scnt += 1.f; }
  }
  float* part = ws + OFF_PCN + 3 * (size_t)N;
  if (lane < CT) {
    float* p = part + (size_t)wid * 48 + lane * 3;
    p[0] = sx; p[1] = sy; p[2] = scnt;
  }
}

// K3: reduce wave partials -> angle_mean[c], cnt[c]. One block, 16 threads/celltype.
__global__ void k3_mean(float* __restrict__ ws, int N, int nwaves) {
  const float* part = ws + OFF_PCN + 3 * (size_t)N;
  int c = threadIdx.x >> 4;
  int sub = threadIdx.x & 15;
  float sx = 0.f, sy = 0.f, sc = 0.f;
  for (int b = sub; b < nwaves; b += 16) {
    const float* p = part + (size_t)b * 48 + c * 3;
    sx += p[0]; sy += p[1]; sc += p[2];
  }
  for (int off = 8; off; off >>= 1) {
    sx += __shfl_xor(sx, off, 64);
    sy += __shfl_xor(sy, off, 64);
    sc += __shfl_xor(sc, off, 64);
  }
  if (sub == 0) {
    ws[OFF_AMEAN + c] = atan2f(sy, sx);
    ws[OFF_CNT + c] = sc;
  }
}

// K4: dev[r] = wrap(angle - angle_mean); per-block LDS min/max -> global atomic min/max.
__global__ __launch_bounds__(256) void k4_dev(const int* __restrict__ ct,
                                              float* __restrict__ ws, int N) {
  __shared__ unsigned smn[CT], smx[CT];
  if (threadIdx.x < CT) { smn[threadIdx.x] = 0xFFFFFFFFu; smx[threadIdx.x] = 0u; }
  __syncthreads();
  const float* amean = ws + OFF_AMEAN;
  const float2* pcn = (const float2*)(ws + OFF_PCN);
  float* dev = ws + OFF_PCN + 2 * (size_t)N;
  int i0 = blockIdx.x * blockDim.x + threadIdx.x;
  int stride = gridDim.x * blockDim.x;
  for (int r = i0; r < N; r += stride) {
    int c = ct[r];
    float2 p = pcn[r];
    float dv = atan2f(p.y, p.x) - amean[c];
    dv = atan2f(sinf(dv), cosf(dv));  // wrap to (-pi,pi], same formula as reference
    dev[r] = dv;
    unsigned e = fenc(dv);
    atomicMin(&smn[c], e);
    atomicMax(&smx[c], e);
  }
  __syncthreads();
  if (threadIdx.x < CT) {
    unsigned* mm = (unsigned*)(ws + OFF_MINMAX);
    atomicMin(&mm[2 * threadIdx.x], smn[threadIdx.x]);
    atomicMax(&mm[2 * threadIdx.x + 1], smx[threadIdx.x]);
  }
}

// K5: per-celltype ratio + keep flag.
__global__ void k5_ratio(float* __restrict__ ws) {
  int c = threadIdx.x;
  if (c >= CT) return;
  unsigned* mm = (unsigned*)(ws + OFF_MINMAX);
  float cnt = ws[OFF_CNT + c];
  float ratio = 1.f;
  if (cnt > 0.f) {
    float mn = fdec(mm[2 * c]);
    float mx = fdec(mm[2 * c + 1]);
    float rng = mx - mn;
    if (rng > 0.f) {
      float target = fminf(MAX_RANGE, rng * EXPANSION);
      ratio = target / rng;
    }
  }
  ws[OFF_RATIO + c] = ratio;
  ws[OFF_KEEP + c] = (cnt <= 2.f) ? 1.f : 0.f;
}

// K6: expanded coords + rank-2 reconstruction, wave-per-row.
__global__ __launch_bounds__(256) void k6_out(const int* __restrict__ ct,
                                              const float* __restrict__ Wd,
                                              const float* __restrict__ bd,
                                              const float* __restrict__ ws,
                                              float* __restrict__ out, int N, int D) {
  const int lane = threadIdx.x & 63;
  const int wid = (int)((blockIdx.x * blockDim.x + threadIdx.x) >> 6);
  const int nw = (int)((gridDim.x * blockDim.x) >> 6);
  const int D4 = D >> 2;
  const float* amean = ws + OFF_AMEAN;
  const float* ratio = ws + OFF_RATIO;
  const float* keepf = ws + OFF_KEEP;
  const float2* pcn = (const float2*)(ws + OFF_PCN);
  const float* dev = ws + OFF_PCN + 2 * (size_t)N;
  const float4* wd0 = (const float4*)Wd;
  const float4* wd1 = (const float4*)(Wd + D);
  const float4* bd4 = (const float4*)bd;
  float* recon = out + 2 * (size_t)N;

  for (int r = wid; r < N; r += nw) {
    int c = ct[r];
    float e0, e1;
    if (keepf[c] != 0.f) {
      float2 p = pcn[r];
      e0 = p.x; e1 = p.y;
    } else {
      float ea = amean[c] + dev[r] * ratio[c];
      e0 = cosf(ea);
      e1 = sinf(ea);
    }
    if (lane == 0) ((float2*)out)[r] = make_float2(e0, e1);
    float4* ro = (float4*)(recon + (size_t)r * D);
    for (int j = lane; j < D4; j += 64) {
      float4 a = wd0[j], b = wd1[j], bb = bd4[j];
      float4 v;
      v.x = fmaf(e0, a.x, fmaf(e1, b.x, bb.x));
      v.y = fmaf(e0, a.y, fmaf(e1, b.y, bb.y));
      v.z = fmaf(e0, a.z, fmaf(e1, b.z, bb.z));
      v.w = fmaf(e0, a.w, fmaf(e1, b.w, bb.w));
      ro[j] = v;
    }
  }
}

extern "C" void kernel_launch(void* const* d_in, const int* in_sizes, int n_in,
                              void* d_out, int out_size, void* d_ws, size_t ws_size,
                              hipStream_t stream) {
  const float* x = (const float*)d_in[0];
  const int* ct = (const int*)d_in[1];
  const float* emb = (const float*)d_in[2];
  const float* Ws = (const float*)d_in[3];
  const float* bs = (const float*)d_in[4];
  const float* Wa = (const float*)d_in[5];
  const float* ba = (const float*)d_in[6];
  const float* gb = (const float*)d_in[7];
  const float* We = (const float*)d_in[8];
  const float* be = (const float*)d_in[9];
  const float* Wd = (const float*)d_in[10];
  const float* bd = (const float*)d_in[11];
  float* out = (float*)d_out;
  float* ws = (float*)d_ws;

  const int N = in_sizes[1];        // 200000
  const int D = in_sizes[4];        // 1000

  k1_setup<<<dim3(CT), dim3(256), 0, stream>>>(emb, Ws, bs, Wa, ba, gb, We, be, ws, D);
  k2_pc<<<dim3(NB_HEAVY), dim3(256), 0, stream>>>(x, ct, ws, N, D);
  k3_mean<<<dim3(1), dim3(256), 0, stream>>>(ws, N, NW);
  int nb4 = (N + 255) / 256;
  k4_dev<<<dim3(nb4), dim3(256), 0, stream>>>(ct, ws, N);
  k5_ratio<<<dim3(1), dim3(64), 0, stream>>>(ws);
  k6_out<<<dim3(NB_HEAVY), dim3(256), 0, stream>>>(ct, Wd, bd, ws, out, N, D);
}

// Round 2
// 448.137 us; speedup vs baseline: 1.2417x; 1.2417x over previous
//
#include <hip/hip_runtime.h>
#include <math.h>

typedef float f32x4 __attribute__((ext_vector_type(4)));

// Problem constants: N=200000, D=1000, C=16, E=4
static constexpr int CT = 16;
static constexpr int ET = 4;
static constexpr float EXPANSION = 2.0f;
static constexpr float MAX_RANGE = 5.65486677646163f;  // 2*pi*0.9

// Workspace layout (float units), D=1000:
static constexpr int OFF_W0 = 0;          // w0[c][d]  (16*1000)
static constexpr int OFF_W1 = 16000;      // w1[c][d]
static constexpr int OFF_CONST = 32000;   // const_c[c][2]
static constexpr int OFF_AMEAN = 32032;   // angle_mean[c]
static constexpr int OFF_RATIO = 32048;   // ratio[c]
static constexpr int OFF_KEEP = 32064;    // keep[c]
static constexpr int OFF_CNT = 32080;     // cnt[c]
static constexpr int OFF_MINMAX = 32096;  // 32 unsigned (min-enc,max-enc)
static constexpr int OFF_PCN = 32128;     // pcn[N][2]; dev at +2N; block partials at +3N

static constexpr int NB_HEAVY = 1024;     // K2 blocks (4 waves each)
static constexpr int NB_OUT = 2048;       // K6 blocks

__device__ __forceinline__ unsigned fenc(float f) {
  unsigned u = __float_as_uint(f);
  return (u & 0x80000000u) ? ~u : (u | 0x80000000u);
}
__device__ __forceinline__ float fdec(unsigned e) {
  unsigned u = (e & 0x80000000u) ? (e ^ 0x80000000u) : ~e;
  return __uint_as_float(u);
}
__device__ __forceinline__ float dot4(f32x4 a, f32x4 b, float acc) {
  acc = fmaf(a.x, b.x, acc); acc = fmaf(a.y, b.y, acc);
  acc = fmaf(a.z, b.z, acc); acc = fmaf(a.w, b.w, acc);
  return acc;
}

// K1: per-celltype effective weights + constants; init minmax slots.
__global__ void k1_setup(const float* __restrict__ emb, const float* __restrict__ Ws,
                         const float* __restrict__ bs, const float* __restrict__ Wa,
                         const float* __restrict__ ba, const float* __restrict__ gb,
                         const float* __restrict__ We, const float* __restrict__ be,
                         float* __restrict__ ws, int D) {
  int c = blockIdx.x;
  float e0 = emb[c * ET + 0], e1 = emb[c * ET + 1], e2 = emb[c * ET + 2], e3 = emb[c * ET + 3];
  float a0 = 0.f, a1 = 0.f;
  for (int d = threadIdx.x; d < D; d += blockDim.x) {
    float sc = e0 * Ws[d] + e1 * Ws[D + d] + e2 * Ws[2 * D + d] + e3 * Ws[3 * D + d] + bs[d];
    float ad = e0 * Wa[d] + e1 * Wa[D + d] + e2 * Wa[2 * D + d] + e3 * Wa[3 * D + d] + ba[d];
    float s1 = 1.f + sc;
    float we0 = We[2 * d], we1 = We[2 * d + 1];
    ws[OFF_W0 + c * D + d] = s1 * we0;
    ws[OFF_W1 + c * D + d] = s1 * we1;
    float t = ad + gb[d];
    a0 += t * we0;
    a1 += t * we1;
  }
  __shared__ float r0[256], r1[256];
  r0[threadIdx.x] = a0;
  r1[threadIdx.x] = a1;
  __syncthreads();
  for (int s = 128; s > 0; s >>= 1) {
    if ((int)threadIdx.x < s) {
      r0[threadIdx.x] += r0[threadIdx.x + s];
      r1[threadIdx.x] += r1[threadIdx.x + s];
    }
    __syncthreads();
  }
  if (threadIdx.x == 0) {
    ws[OFF_CONST + c * 2 + 0] = r0[0] + be[0];
    ws[OFF_CONST + c * 2 + 1] = r1[0] + be[1];
  }
  if (blockIdx.x == 0 && threadIdx.x < CT) {
    unsigned* mm = (unsigned*)(ws + OFF_MINMAX);
    mm[2 * threadIdx.x] = 0xFFFFFFFFu;
    mm[2 * threadIdx.x + 1] = 0u;
  }
}

// K2: 4 rows per wave per iteration; nontemporal x stream; per-block partials.
__global__ __launch_bounds__(256, 4) void k2_pc(const float* __restrict__ x,
                                                const int* __restrict__ ct,
                                                float* __restrict__ ws, int N, int D) {
  const int lane = threadIdx.x & 63;
  const int wv = threadIdx.x >> 6;
  const int wid = (int)blockIdx.x * 4 + wv;
  const int nw = (int)gridDim.x * 4;
  const int D4 = D >> 2;
  const float* constc = ws + OFF_CONST;
  float2* pcn = (float2*)(ws + OFF_PCN);
  const f32x4* xb = (const f32x4*)x;
  const f32x4* w0b = (const f32x4*)(ws + OFF_W0);
  const f32x4* w1b = (const f32x4*)(ws + OFF_W1);

  __shared__ float sh[4][CT][3];
  float sx = 0.f, sy = 0.f, scnt = 0.f;  // lane == c holds partial for celltype c

  for (int r0 = wid * 4; r0 < N; r0 += nw * 4) {
    int c0 = ct[r0 + 0], c1 = ct[r0 + 1], c2 = ct[r0 + 2], c3 = ct[r0 + 3];
    size_t xr = (size_t)r0 * D4;
    int o0 = c0 * D4, o1 = c1 * D4, o2 = c2 * D4, o3 = c3 * D4;
    float a00 = 0.f, a01 = 0.f, a10 = 0.f, a11 = 0.f;
    float a20 = 0.f, a21 = 0.f, a30 = 0.f, a31 = 0.f;
#pragma unroll
    for (int k = 0; k < 4; ++k) {
      int j = lane + 64 * k;
      if (j < D4) {
        f32x4 xv0 = __builtin_nontemporal_load(&xb[xr + j]);
        f32x4 xv1 = __builtin_nontemporal_load(&xb[xr + D4 + j]);
        f32x4 xv2 = __builtin_nontemporal_load(&xb[xr + 2 * D4 + j]);
        f32x4 xv3 = __builtin_nontemporal_load(&xb[xr + 3 * D4 + j]);
        a00 = dot4(xv0, w0b[o0 + j], a00); a01 = dot4(xv0, w1b[o0 + j], a01);
        a10 = dot4(xv1, w0b[o1 + j], a10); a11 = dot4(xv1, w1b[o1 + j], a11);
        a20 = dot4(xv2, w0b[o2 + j], a20); a21 = dot4(xv2, w1b[o2 + j], a21);
        a30 = dot4(xv3, w0b[o3 + j], a30); a31 = dot4(xv3, w1b[o3 + j], a31);
      }
    }
#pragma unroll
    for (int off = 32; off; off >>= 1) {
      a00 += __shfl_xor(a00, off, 64); a01 += __shfl_xor(a01, off, 64);
      a10 += __shfl_xor(a10, off, 64); a11 += __shfl_xor(a11, off, 64);
      a20 += __shfl_xor(a20, off, 64); a21 += __shfl_xor(a21, off, 64);
      a30 += __shfl_xor(a30, off, 64); a31 += __shfl_xor(a31, off, 64);
    }
#define FINALIZE(AA, BB, CC, RR)                                   \
    {                                                              \
      float p0 = AA + constc[2 * CC], p1 = BB + constc[2 * CC + 1];\
      float nrm = sqrtf(p0 * p0 + p1 * p1) + 1e-8f;                \
      float q0 = p0 / nrm, q1 = p1 / nrm;                          \
      if (lane == 0) pcn[RR] = make_float2(q0, q1);                \
      if (lane == CC) { sx += q0; sy += q1; scnt += 1.f; }         \
    }
    FINALIZE(a00, a01, c0, r0 + 0)
    FINALIZE(a10, a11, c1, r0 + 1)
    FINALIZE(a20, a21, c2, r0 + 2)
    FINALIZE(a30, a31, c3, r0 + 3)
#undef FINALIZE
  }

  if (lane < CT) {
    sh[wv][lane][0] = sx; sh[wv][lane][1] = sy; sh[wv][lane][2] = scnt;
  }
  __syncthreads();
  if (threadIdx.x < CT) {
    int c = threadIdx.x;
    float* part = ws + OFF_PCN + 3 * (size_t)N + (size_t)blockIdx.x * 48 + c * 3;
    part[0] = sh[0][c][0] + sh[1][c][0] + sh[2][c][0] + sh[3][c][0];
    part[1] = sh[0][c][1] + sh[1][c][1] + sh[2][c][1] + sh[3][c][1];
    part[2] = sh[0][c][2] + sh[1][c][2] + sh[2][c][2] + sh[3][c][2];
  }
}

// K3: reduce block partials -> angle_mean[c], cnt[c]. One block, 16 threads/celltype.
__global__ void k3_mean(float* __restrict__ ws, int N, int nparts) {
  const float* part = ws + OFF_PCN + 3 * (size_t)N;
  int c = threadIdx.x >> 4;
  int sub = threadIdx.x & 15;
  float sx = 0.f, sy = 0.f, sc = 0.f;
  for (int b = sub; b < nparts; b += 16) {
    const float* p = part + (size_t)b * 48 + c * 3;
    sx += p[0]; sy += p[1]; sc += p[2];
  }
  for (int off = 8; off; off >>= 1) {
    sx += __shfl_xor(sx, off, 64);
    sy += __shfl_xor(sy, off, 64);
    sc += __shfl_xor(sc, off, 64);
  }
  if (sub == 0) {
    ws[OFF_AMEAN + c] = atan2f(sy, sx);
    ws[OFF_CNT + c] = sc;
  }
}

// K4: dev[r] = wrap(angle - angle_mean); block-local then global atomic min/max.
__global__ __launch_bounds__(256) void k4_dev(const int* __restrict__ ct,
                                              float* __restrict__ ws, int N) {
  __shared__ unsigned smn[CT], smx[CT];
  if (threadIdx.x < CT) { smn[threadIdx.x] = 0xFFFFFFFFu; smx[threadIdx.x] = 0u; }
  __syncthreads();
  const float* amean = ws + OFF_AMEAN;
  const float2* pcn = (const float2*)(ws + OFF_PCN);
  float* dev = ws + OFF_PCN + 2 * (size_t)N;
  int i0 = blockIdx.x * blockDim.x + threadIdx.x;
  int stride = gridDim.x * blockDim.x;
  for (int r = i0; r < N; r += stride) {
    int c = ct[r];
    float2 p = pcn[r];
    float dv = atan2f(p.y, p.x) - amean[c];
    dv = atan2f(sinf(dv), cosf(dv));  // wrap, same formula as reference
    dev[r] = dv;
    unsigned e = fenc(dv);
    atomicMin(&smn[c], e);
    atomicMax(&smx[c], e);
  }
  __syncthreads();
  if (threadIdx.x < CT) {
    unsigned* mm = (unsigned*)(ws + OFF_MINMAX);
    atomicMin(&mm[2 * threadIdx.x], smn[threadIdx.x]);
    atomicMax(&mm[2 * threadIdx.x + 1], smx[threadIdx.x]);
  }
}

// K5: per-celltype ratio + keep flag.
__global__ void k5_ratio(float* __restrict__ ws) {
  int c = threadIdx.x;
  if (c >= CT) return;
  unsigned* mm = (unsigned*)(ws + OFF_MINMAX);
  float cnt = ws[OFF_CNT + c];
  float ratio = 1.f;
  if (cnt > 0.f) {
    float mn = fdec(mm[2 * c]);
    float mx = fdec(mm[2 * c + 1]);
    float rng = mx - mn;
    if (rng > 0.f) {
      float target = fminf(MAX_RANGE, rng * EXPANSION);
      ratio = target / rng;
    }
  }
  ws[OFF_RATIO + c] = ratio;
  ws[OFF_KEEP + c] = (cnt <= 2.f) ? 1.f : 0.f;
}

// K6: expanded coords + rank-2 reconstruction; weights preloaded in registers,
// nontemporal streaming stores.
__global__ __launch_bounds__(256, 4) void k6_out(const int* __restrict__ ct,
                                                 const float* __restrict__ Wd,
                                                 const float* __restrict__ bd,
                                                 const float* __restrict__ ws,
                                                 float* __restrict__ out, int N, int D) {
  const int lane = threadIdx.x & 63;
  const int wid = (int)blockIdx.x * 4 + (threadIdx.x >> 6);
  const int nw = (int)gridDim.x * 4;
  const int D4 = D >> 2;
  const float* amean = ws + OFF_AMEAN;
  const float* ratio = ws + OFF_RATIO;
  const float* keepf = ws + OFF_KEEP;
  const float2* pcn = (const float2*)(ws + OFF_PCN);
  const float* dev = ws + OFF_PCN + 2 * (size_t)N;
  const f32x4* wd0 = (const f32x4*)Wd;
  const f32x4* wd1 = (const f32x4*)(Wd + D);
  const f32x4* bd4 = (const f32x4*)bd;
  float* recon = out + 2 * (size_t)N;

  f32x4 wa[4], wb[4], wc[4];
#pragma unroll
  for (int k = 0; k < 4; ++k) {
    int j = lane + 64 * k;
    if (j < D4) { wa[k] = wd0[j]; wb[k] = wd1[j]; wc[k] = bd4[j]; }
    else { wa[k] = (f32x4){0.f,0.f,0.f,0.f}; wb[k] = wa[k]; wc[k] = wa[k]; }
  }

  for (int r = wid; r < N; r += nw) {
    int c = ct[r];
    float e0, e1;
    if (keepf[c] != 0.f) {
      float2 p = pcn[r];
      e0 = p.x; e1 = p.y;
    } else {
      float ea = amean[c] + dev[r] * ratio[c];
      e0 = cosf(ea);
      e1 = sinf(ea);
    }
    if (lane == 0) ((float2*)out)[r] = make_float2(e0, e1);
    f32x4* ro = (f32x4*)(recon + (size_t)r * D);
#pragma unroll
    for (int k = 0; k < 4; ++k) {
      int j = lane + 64 * k;
      if (j < D4) {
        f32x4 v;
        v.x = fmaf(e0, wa[k].x, fmaf(e1, wb[k].x, wc[k].x));
        v.y = fmaf(e0, wa[k].y, fmaf(e1, wb[k].y, wc[k].y));
        v.z = fmaf(e0, wa[k].z, fmaf(e1, wb[k].z, wc[k].z));
        v.w = fmaf(e0, wa[k].w, fmaf(e1, wb[k].w, wc[k].w));
        __builtin_nontemporal_store(v, &ro[j]);
      }
    }
  }
}

extern "C" void kernel_launch(void* const* d_in, const int* in_sizes, int n_in,
                              void* d_out, int out_size, void* d_ws, size_t ws_size,
                              hipStream_t stream) {
  const float* x = (const float*)d_in[0];
  const int* ct = (const int*)d_in[1];
  const float* emb = (const float*)d_in[2];
  const float* Ws = (const float*)d_in[3];
  const float* bs = (const float*)d_in[4];
  const float* Wa = (const float*)d_in[5];
  const float* ba = (const float*)d_in[6];
  const float* gb = (const float*)d_in[7];
  const float* We = (const float*)d_in[8];
  const float* be = (const float*)d_in[9];
  const float* Wd = (const float*)d_in[10];
  const float* bd = (const float*)d_in[11];
  float* out = (float*)d_out;
  float* ws = (float*)d_ws;

  const int N = in_sizes[1];   // 200000
  const int D = in_sizes[4];   // 1000

  k1_setup<<<dim3(CT), dim3(256), 0, stream>>>(emb, Ws, bs, Wa, ba, gb, We, be, ws, D);
  k2_pc<<<dim3(NB_HEAVY), dim3(256), 0, stream>>>(x, ct, ws, N, D);
  k3_mean<<<dim3(1), dim3(256), 0, stream>>>(ws, N, NB_HEAVY);
  int nb4 = (N + 255) / 256;
  k4_dev<<<dim3(nb4), dim3(256), 0, stream>>>(ct, ws, N);
  k5_ratio<<<dim3(1), dim3(64), 0, stream>>>(ws);
  k6_out<<<dim3(NB_OUT), dim3(256), 0, stream>>>(ct, Wd, bd, ws, out, N, D);
}